// Round 2
// baseline (257.816 us; speedup 1.0000x reference)
//
#include <hip/hip_runtime.h>
#include <math.h>

#define B_ 64
#define T_ 64
#define V_ 8192

// log(1e-8), log(1 - 8190e-8)
#define L0_ (-18.420680743952367f)
#define L1_ (-8.190335e-05f)
#define HI_ (0.99991810f)
#define EPS_ (1e-8f)

// ws layout (4-byte words, all zeroed by hipMemsetAsync each call):
//   [0    .. 4095]  int   colmax[64*64]     (float bits, probs > 0 so int-monotone)
//   [4096 .. 4223]  float acc[64*2]         (bce eos-sum, bce head-sum per batch)
//   [4224 .. 4287]  float labelpart[64]
//   [4288 .. 4351]  float eospart[64]
//   [4352 .. 4415]  int   batchcnt[64]
//   [4416]          int   globalcnt
#define WS_WORDS 4420

__device__ __forceinline__ float waveReduceMax(float v) {
    #pragma unroll
    for (int off = 32; off; off >>= 1) v = fmaxf(v, __shfl_xor(v, off));
    return v;
}
__device__ __forceinline__ float waveReduceSum(float v) {
    #pragma unroll
    for (int off = 32; off; off >>= 1) v += __shfl_xor(v, off);
    return v;
}

// One block per row (b*64+n). Streams the row (softmax stats), contributes its
// row-local terms via device atomics, last block of each batch does the batch
// tail, last batch tail does the final reduction -> out.
__global__ __launch_bounds__(256) void k_fused(const float* __restrict__ logits,
                                               const int* __restrict__ targets,
                                               int* __restrict__ wsi,
                                               float* __restrict__ out) {
    float* wsf       = (float*)wsi;
    int*   colmax    = wsi;
    float* acc       = wsf + 4096;
    float* labelpart = wsf + 4224;
    float* eospart   = wsf + 4288;
    int*   batchcnt  = wsi + 4352;
    int*   globalcnt = wsi + 4416;

    const int row = blockIdx.x;
    const int b   = row >> 6;
    const int n   = row & 63;
    const int tid = threadIdx.x;

    // ---- phase 1: stream row, softmax stats (register-resident, 1 HBM pass) ----
    const float4* rp4 = (const float4*)(logits + (size_t)row * V_);
    float4 v[8];
    float lmax = -3.4e38f;
    #pragma unroll
    for (int k = 0; k < 8; ++k) {
        v[k] = rp4[tid + (k << 8)];
        lmax = fmaxf(lmax, fmaxf(fmaxf(v[k].x, v[k].y), fmaxf(v[k].z, v[k].w)));
    }

    const int lane = tid & 63, wid = tid >> 6;
    __shared__ float sredm[4], sreds[4], s_l0;
    if (tid == 0) s_l0 = v[0].x;                  // logits[row][0]
    float wm = waveReduceMax(lmax);
    if (lane == 0) sredm[wid] = wm;
    __syncthreads();
    const float M = fmaxf(fmaxf(sredm[0], sredm[1]), fmaxf(sredm[2], sredm[3]));

    float lsum = 0.0f;
    #pragma unroll
    for (int k = 0; k < 8; ++k) {
        lsum += __expf(v[k].x - M) + __expf(v[k].y - M) +
                __expf(v[k].z - M) + __expf(v[k].w - M);
    }
    float ws = waveReduceSum(lsum);
    if (lane == 0) sreds[wid] = ws;
    __syncthreads();

    // ---- phase 2: wave 0 only ----
    if (tid >= 64) return;
    const float Z  = sreds[0] + sreds[1] + sreds[2] + sreds[3];
    const float iZ = 1.0f / Z;
    const float p0 = __expf(s_l0 - M) * iZ;

    const int  j     = tid;
    const int  tj    = targets[b * 64 + j];
    const bool headj = (tj != 0) && (tj != 8192);
    const int  tn    = __shfl(tj, n);             // this row's own target
    const bool head_n = (tn != 0) && (tn != 8192);
    const bool isz_n  = (tn == 0);

    if (head_n) {
        // gather probs[row, t_j] for head cols j (row is L1/L2-hot)
        float pj = 0.0f;
        if (headj) {
            pj = __expf(logits[(size_t)row * V_ + tj] - M) * iZ;
            atomicMax(&colmax[b * 64 + j], __float_as_int(pj));
        }
        float rm = waveReduceMax(pj);
        if (j == 0) {
            // dist2 min over m: -L0*(1-p0) - (L1-L0)*max_head_m probs[n, t_m]
            float t2 = (-L0_) * (1.0f - p0) - (L1_ - L0_) * rm;
            atomicAdd(&labelpart[b], t2);
        }
    }
    if (j == 0) {
        if (isz_n)  atomicAdd(&acc[b * 2 + 0], -__logf(p0));
        if (head_n) atomicAdd(&acc[b * 2 + 1], -__logf(1.0f - p0));
    }

    __threadfence();                              // release data atomics before counter
    int old = 0;
    if (j == 0) old = atomicAdd(&batchcnt[b], 1);
    old = __shfl(old, 0);

    if (old == 63) {
        // ---- batch tail: all 64 rows of batch b contributed ----
        float t1 = 0.0f;
        if (headj) {
            float cm = __int_as_float(atomicMax(&colmax[b * 64 + j], 0)); // coherent read
            cm = fminf(fmaxf(cm, EPS_), HI_);
            t1 = -__logf(cm);
        }
        float t1sum = waveReduceSum(t1);
        unsigned long long hb = __ballot(headj);
        unsigned long long zb = __ballot(tj == 0);
        if (j == 0) {
            float ca = (float)__popcll(zb);
            float ch = (float)__popcll(hb);
            float asum = atomicAdd(&acc[b * 2 + 0], 0.0f);   // coherent read
            float hsum = atomicAdd(&acc[b * 2 + 1], 0.0f);
            float eos_b = 0.5f * asum / (ca + EPS_) + 0.5f * hsum / (ch + EPS_);
            atomicAdd(&labelpart[b], t1sum);
            atomicAdd(&eospart[b], eos_b);
        }
        __threadfence();
        int g = 0;
        if (j == 0) g = atomicAdd(globalcnt, 1);
        g = __shfl(g, 0);
        if (g == 63) {
            // ---- global tail: all 64 batch tails done ----
            float lj = atomicAdd(&labelpart[j], 0.0f);       // coherent reads
            float ej = atomicAdd(&eospart[j], 0.0f);
            float L = waveReduceSum(lj);
            float E = waveReduceSum(ej);
            if (j == 0) { out[0] = L; out[1] = E * (1.0f / 64.0f); }
        }
    }
}

extern "C" void kernel_launch(void* const* d_in, const int* in_sizes, int n_in,
                              void* d_out, int out_size, void* d_ws, size_t ws_size,
                              hipStream_t stream) {
    const float* logits  = (const float*)d_in[0];
    const int*   targets = (const int*)d_in[1];
    float* out = (float*)d_out;

    hipMemsetAsync(d_ws, 0, WS_WORDS * sizeof(int), stream);
    k_fused<<<dim3(B_ * T_), dim3(256), 0, stream>>>(logits, targets, (int*)d_ws, out);
}

// Round 3
// 32.598 us; speedup vs baseline: 7.9090x; 7.9090x over previous
//
#include <hip/hip_runtime.h>
#include <math.h>

#define B_ 64
#define T_ 64
#define V_ 8192

// log(1e-8), log(1 - 8190e-8)
#define L0_ (-18.420680743952367f)
#define L1_ (-8.190335e-05f)
#define HI_ (0.99991810f)
#define EPS_ (1e-8f)

// ws layout (floats), all fully overwritten every call (no memset needed):
//   P     [4096*64]  @ 0        probs[row, t_j] for head rows/cols, else 0
//   t2row [4096]     @ 262144   dist2 row term (0 for non-head rows)
//   bA    [4096]     @ 266240   -log(p0) for eos-target rows, else 0
//   bH    [4096]     @ 270336   -log(1-p0) for head rows, else 0
#define OFF_T2 262144
#define OFF_BA 266240
#define OFF_BH 270336

__device__ __forceinline__ float waveReduceMax(float v) {
    #pragma unroll
    for (int off = 32; off; off >>= 1) v = fmaxf(v, __shfl_xor(v, off));
    return v;
}
__device__ __forceinline__ float waveReduceSum(float v) {
    #pragma unroll
    for (int off = 32; off; off >>= 1) v += __shfl_xor(v, off);
    return v;
}

// One block per row (b*64+n). Streams the row once (softmax stats), then wave 0
// gathers the 64 target probs from the L1/L2-hot row and plain-writes dense
// per-row results to ws. No cross-block atomics, no fences.
__global__ __launch_bounds__(256) void k_row(const float* __restrict__ logits,
                                             const int* __restrict__ targets,
                                             float* __restrict__ wsf,
                                             float* __restrict__ out) {
    const int row = blockIdx.x;
    const int b   = row >> 6;
    const int n   = row & 63;
    const int tid = threadIdx.x;
    if (row == 0 && tid < 2) out[tid] = 0.0f;  // zeroed before k_batch (stream order)

    // ---- single-pass row streaming, register-resident ----
    const float4* rp4 = (const float4*)(logits + (size_t)row * V_);
    float4 v[8];
    float lmax = -3.4e38f;
    #pragma unroll
    for (int k = 0; k < 8; ++k) {
        v[k] = rp4[tid + (k << 8)];
        lmax = fmaxf(lmax, fmaxf(fmaxf(v[k].x, v[k].y), fmaxf(v[k].z, v[k].w)));
    }

    const int lane = tid & 63, wid = tid >> 6;
    __shared__ float sredm[4], sreds[4], s_l0;
    if (tid == 0) s_l0 = v[0].x;               // logits[row][0]
    float wm = waveReduceMax(lmax);
    if (lane == 0) sredm[wid] = wm;
    __syncthreads();
    const float M = fmaxf(fmaxf(sredm[0], sredm[1]), fmaxf(sredm[2], sredm[3]));

    float lsum = 0.0f;
    #pragma unroll
    for (int k = 0; k < 8; ++k) {
        lsum += __expf(v[k].x - M) + __expf(v[k].y - M) +
                __expf(v[k].z - M) + __expf(v[k].w - M);
    }
    float ws = waveReduceSum(lsum);
    if (lane == 0) sreds[wid] = ws;
    __syncthreads();

    // ---- wave 0: per-row epilogue ----
    if (tid >= 64) return;
    const float Z  = sreds[0] + sreds[1] + sreds[2] + sreds[3];
    const float iZ = 1.0f / Z;
    const float p0 = __expf(s_l0 - M) * iZ;

    const int  j      = tid;
    const int  tj     = targets[b * 64 + j];
    const bool headj  = (tj != 0) && (tj != 8192);
    const int  tn     = __shfl(tj, n);         // this row's own target
    const bool head_n = (tn != 0) && (tn != 8192);
    const bool isz_n  = (tn == 0);

    float pj = 0.0f;
    if (head_n && headj)                       // row is L1/L2-hot: cheap re-read
        pj = __expf(logits[(size_t)row * V_ + tj] - M) * iZ;
    wsf[(size_t)row * 64 + j] = pj;            // coalesced 256B store

    const float rm = waveReduceMax(pj);
    if (j == 0) {
        wsf[OFF_T2 + row] = head_n ? ((-L0_) * (1.0f - p0) - (L1_ - L0_) * rm) : 0.0f;
        wsf[OFF_BA + row] = isz_n  ? -__logf(p0)        : 0.0f;
        wsf[OFF_BH + row] = head_n ? -__logf(1.0f - p0) : 0.0f;
    }
}

// One block per batch b: col-max over the 64x64 P tile + cheap sums -> out.
__global__ __launch_bounds__(256) void k_batch(const int* __restrict__ targets,
                                               const float* __restrict__ wsf,
                                               float* __restrict__ out) {
    const int b   = blockIdx.x;
    const int tid = threadIdx.x;
    const int j   = tid & 63, g = tid >> 6;    // 4 groups x 16 rows

    const float* Pb = wsf + (size_t)b * 64 * 64;
    float cm = 0.0f;
    #pragma unroll
    for (int nn = 0; nn < 16; ++nn)
        cm = fmaxf(cm, Pb[(g * 16 + nn) * 64 + j]);   // coalesced per group

    __shared__ float scm[256];
    scm[tid] = cm;
    __syncthreads();

    if (tid >= 64) return;
    const float cmj = fmaxf(fmaxf(scm[j], scm[64 + j]),
                            fmaxf(scm[128 + j], scm[192 + j]));
    const int  tj    = targets[b * 64 + j];
    const bool headj = (tj != 0) && (tj != 8192);

    float t1 = headj ? -__logf(fminf(fmaxf(cmj, EPS_), HI_)) : 0.0f;
    float lab = t1 + wsf[OFF_T2 + b * 64 + j];
    float a   = wsf[OFF_BA + b * 64 + j];
    float h   = wsf[OFF_BH + b * 64 + j];
    float cz  = (tj == 0) ? 1.0f : 0.0f;
    float ch  = headj     ? 1.0f : 0.0f;

    lab = waveReduceSum(lab);
    a   = waveReduceSum(a);
    h   = waveReduceSum(h);
    cz  = waveReduceSum(cz);
    ch  = waveReduceSum(ch);
    if (tid == 0) {
        atomicAdd(&out[0], lab);
        atomicAdd(&out[1], (0.5f * a / (cz + EPS_) + 0.5f * h / (ch + EPS_)) * (1.0f / 64.0f));
    }
}

extern "C" void kernel_launch(void* const* d_in, const int* in_sizes, int n_in,
                              void* d_out, int out_size, void* d_ws, size_t ws_size,
                              hipStream_t stream) {
    const float* logits  = (const float*)d_in[0];
    const int*   targets = (const int*)d_in[1];
    float* out = (float*)d_out;
    float* wsf = (float*)d_ws;   // ~1.1 MB used, fully overwritten each call

    k_row<<<dim3(B_ * T_), dim3(256), 0, stream>>>(logits, targets, wsf, out);
    k_batch<<<dim3(B_), dim3(256), 0, stream>>>(targets, wsf, out);
}